// Round 8
// baseline (4411.138 us; speedup 1.0000x reference)
//
#include <hip/hip_runtime.h>

typedef __bf16 bf16;
typedef bf16 bf16x8 __attribute__((ext_vector_type(8)));
typedef bf16 bf16x4 __attribute__((ext_vector_type(4)));
typedef float f32x4 __attribute__((ext_vector_type(4)));

#define B_ 8
#define S_ 2048
#define D_ 1024
#define NH_ 8
#define HD_ 128
#define UPP 2816
#define ROWS (B_*S_)

__device__ __forceinline__ void gload_lds16(const void* gsrc, void* ldsdst) {
  __builtin_amdgcn_global_load_lds(
      (const __attribute__((address_space(1))) void*)gsrc,
      (__attribute__((address_space(3))) void*)ldsdst, 16, 0, 0);
}

// ---------------- weight packing ----------------
// Wg/R: [4][NH][HD][HD] -> per-head [512][128] bf16 with col j=(o>>4)*64+g*16+(o&15)
// Pre-scaled by log2(e) per gate (2*log2(e) for z): recurrence in exp2/log2 domain.
__global__ __launch_bounds__(256) void pack_wgr_kernel(
    const float* __restrict__ Wg, const float* __restrict__ R, const float* __restrict__ bv,
    bf16* __restrict__ Wgpk, bf16* __restrict__ Rpk, float* __restrict__ biaspk)
{
  const float K2 = 1.442695040888963f;
  int idx = blockIdx.x * 256 + threadIdx.x;
  if (idx < 8*512*128) {
    int k = idx & 127, j = (idx >> 7) & 511, n = idx >> 16;
    int g = (j >> 4) & 3, o = ((j >> 6) << 4) | (j & 15);
    float sc = (g == 2) ? 2.f*K2 : K2;
    size_t src = (((size_t)(g*8 + n)*128 + o)*128 + k);
    Wgpk[idx] = (bf16)(Wg[src] * sc);
    Rpk[idx]  = (bf16)(R[src] * sc);
  }
  if (idx < 8*512) {
    int j = idx & 511, n = idx >> 9;
    int g = (j >> 4) & 3, o = ((j >> 6) << 4) | (j & 15);
    float sc = (g == 2) ? 2.f*K2 : K2;
    biaspk[idx] = bv[g*1024 + n*128 + o] * sc;
  }
}

// out[j][k] = (k<K_in && j<N_in) ? in[k][j] : 0 ;  out dims [N_out][K_out]
__global__ __launch_bounds__(256) void packT_kernel(
    const float* __restrict__ in, bf16* __restrict__ out,
    int K_out, int N_out, int K_in, int N_in)
{
  __shared__ float tile[64][65];
  int k0 = blockIdx.x * 64, j0 = blockIdx.y * 64;
  int tj = threadIdx.x & 63, t4 = threadIdx.x >> 6;
  #pragma unroll
  for (int p = 0; p < 16; ++p) {
    int kk = p*4 + t4, k = k0 + kk, j = j0 + tj;
    tile[kk][tj] = (k < K_in && j < N_in) ? in[(size_t)k * N_in + j] : 0.f;
  }
  __syncthreads();
  #pragma unroll
  for (int p = 0; p < 16; ++p) {
    int jj = p*4 + t4, j = j0 + jj, k = k0 + tj;
    if (j < N_out && k < K_out) out[(size_t)j * K_out + k] = (bf16)tile[tj][jj];
  }
}

// ---------------- rmsnorm1: x -> xn (bf16) ----------------
__global__ __launch_bounds__(256) void rmsnorm1_kernel(
    const float* __restrict__ x, const float* __restrict__ w, bf16* __restrict__ xn)
{
  const int row = blockIdx.x, t = threadIdx.x;
  const size_t base = (size_t)row * D_;
  float4 xv = ((const float4*)(x + base))[t];
  float p = xv.x*xv.x + xv.y*xv.y + xv.z*xv.z + xv.w*xv.w;
  #pragma unroll
  for (int m = 1; m <= 32; m <<= 1) p += __shfl_xor(p, m);
  __shared__ float red[4];
  if ((t & 63) == 0) red[t >> 6] = p;
  __syncthreads();
  float rs = rsqrtf((red[0]+red[1]+red[2]+red[3]) * (1.f/1024.f) + 1e-6f);
  float4 wv = ((const float4*)w)[t];
  bf16x4 o;
  o[0] = (bf16)(xv.x*rs*wv.x); o[1] = (bf16)(xv.y*rs*wv.y);
  o[2] = (bf16)(xv.z*rs*wv.z); o[3] = (bf16)(xv.w*rs*wv.w);
  ((bf16x4*)(xn + base))[t] = o;
}

// ---------------- GEMM: C[M,N] = A[M,K] * B[N,K]^T  (both bf16, row-major) ----------------
#define BM 128
#define BN 128
#define BKK 64
// MODE 0: gx (per-head via blockIdx.z, bf16 out + bias)
// MODE 1: bf16 out
// MODE 2: f32 out + residual (res may alias Cf)
// MODE 3: bf16 out = silu(gatein[off]) * v  (gatein may alias Cb)
template<int MODE>
__global__ __launch_bounds__(256) void gemm_bt(
    const bf16* __restrict__ A, int lda,
    const bf16* __restrict__ B, int ldb,
    float* Cf, bf16* Cb, int ldc,
    const float* __restrict__ bias, const float* res, const bf16* gatein, int K)
{
  __shared__ __align__(16) bf16 As[BM*BKK];
  __shared__ __align__(16) bf16 Bs[BN*BKK];
  if constexpr (MODE == 0) {
    const int h = blockIdx.z;
    A += h * HD_;
    B += (size_t)h * (512*128);
    Cb += (size_t)h * ((size_t)ROWS * 512);
    bias += h * 512;
  }
  const int tid = threadIdx.x;
  const int lane = tid & 63, wave = tid >> 6;
  const int row0 = blockIdx.y * BM, col0 = blockIdx.x * BN;
  const int srow = lane >> 3, scol = (lane & 7) * 8;
  const int wr = (wave >> 1) * 64, wc = (wave & 1) * 64;
  const int fr = lane & 15, fg = lane >> 4;
  f32x4 acc[4][4] = {};

  for (int k0 = 0; k0 < K; k0 += BKK) {
    __syncthreads();
    #pragma unroll
    for (int c = 0; c < 4; ++c) {
      const int slot = wave * 4 + c;
      const int r = slot * 8 + srow;
      gload_lds16(A + (size_t)(row0 + r) * lda + (k0 + scol), &As[slot * 512]);
      gload_lds16(B + (size_t)(col0 + r) * ldb + (k0 + scol), &Bs[slot * 512]);
    }
    __syncthreads();
    #pragma unroll
    for (int kk = 0; kk < 2; ++kk) {
      bf16x8 af[4], bfv[4];
      #pragma unroll
      for (int m = 0; m < 4; ++m)
        af[m] = *(const bf16x8*)&As[(wr + m*16 + fr)*BKK + kk*32 + fg*8];
      #pragma unroll
      for (int nn = 0; nn < 4; ++nn)
        bfv[nn] = *(const bf16x8*)&Bs[(wc + nn*16 + fr)*BKK + kk*32 + fg*8];
      #pragma unroll
      for (int m = 0; m < 4; ++m)
        #pragma unroll
        for (int nn = 0; nn < 4; ++nn)
          acc[m][nn] = __builtin_amdgcn_mfma_f32_16x16x32_bf16(af[m], bfv[nn], acc[m][nn], 0, 0, 0);
    }
  }

  #pragma unroll
  for (int m = 0; m < 4; ++m) {
    const int rbase = row0 + wr + m*16 + fg*4;
    #pragma unroll
    for (int nn = 0; nn < 4; ++nn) {
      const int col = col0 + wc + nn*16 + fr;
      #pragma unroll
      for (int j = 0; j < 4; ++j) {
        const size_t off = (size_t)(rbase + j) * ldc + col;
        float v = acc[m][nn][j];
        if constexpr (MODE == 0) Cb[off] = (bf16)(v + bias[col]);
        if constexpr (MODE == 1) Cb[off] = (bf16)v;
        if constexpr (MODE == 2) Cf[off] = v + res[off];
        if constexpr (MODE == 3) {
          float gf = (float)gatein[off];
          Cb[off] = (bf16)(gf / (1.f + __expf(-gf)) * v);
        }
      }
    }
  }
}

// ---------------- sLSTM recurrence: 32 blocks = (head, batch-pair), 8 waves ----------------
// A=Rpk rows j, B=H (cols alternate batch 0/1) -> C[j][b].
// Wave w owns j in [w*64, w*64+64): tile index == gate g -> 16 MFMA/wave/step.
// POINTWISE IN MFMA LAYOUT (no redistribution): lane with b16<2 holds
// acc[g][jj] = preact(gate g, o = w*16 + fg*4 + jj, batch b16) -> per-lane state
// cS[4]/nS[4]/mS[4]; h written as ONE ds_write_b64 (bf16x4) + 8B global store.
// No LDS scratch on the critical path; one lgkmcnt(0)+s_barrier per step,
// vmcnt never drained (gx prefetch distance 2, rotating bf16x4 buffers).
__global__ __launch_bounds__(512, 1) void recur_kernel(
    const bf16* __restrict__ gx, const bf16* __restrict__ Rpk,
    bf16* __restrict__ hs, float* __restrict__ stateOut)
{
  const int n  = blockIdx.x >> 2;       // head
  const int bp = blockIdx.x & 3;        // batch pair
  const int tid = threadIdx.x, w = tid >> 6, l = tid & 63;
  const int b16 = l & 15, fg = l >> 4;
  const bool act = (b16 < 2);
  const int b   = bp*2 + b16;           // global batch (valid when act)
  const int o0  = w*16 + fg*4;          // first of this lane's 4 outputs

  __shared__ __align__(16) bf16 H[2][2][136];          // [buf][bl][o]
  for (int i = tid; i < 2*2*136; i += 512) ((bf16*)H)[i] = (bf16)0.f;
  __syncthreads();

  // R fragments, register-resident: 4 gate-tiles x 4 k-slices (64 VGPR)
  bf16x8 rf[4][4];
  #pragma unroll
  for (int g = 0; g < 4; ++g)
    #pragma unroll
    for (int kk = 0; kk < 4; ++kk)
      rf[g][kk] = *(const bf16x8*)&Rpk[(size_t)n*65536 + (size_t)(w*64 + g*16 + b16)*128 + kk*32 + fg*8];

  // pinned zero accumulator source
  f32x4 zv = {0.f, 0.f, 0.f, 0.f};
  asm volatile("" : "+v"(zv));

  float cS[4] = {}, nS[4] = {}, mS[4] = {}, hv[4] = {};

  // gx element base: j(g,jj) = w*64 + g*16 + fg*4 + jj ; per-step advance = 512
  const bf16* gxp = gx + (size_t)n * ROWS * 512 + (size_t)b * S_ * 512
                    + (size_t)w * 64 + fg*4;
  bf16* hsp = hs + (size_t)b * S_ * D_ + n * HD_ + o0;

  bf16x4 ga[4][4];   // rotating gate-preact buffers [slot][g] (active lanes only)
  if (act) {
    #pragma unroll
    for (int g = 0; g < 4; ++g) {
      ga[0][g] = *(const bf16x4*)(gxp + (size_t)0*512 + g*16);
      ga[1][g] = *(const bf16x4*)(gxp + (size_t)1*512 + g*16);
    }
  }

  auto step = [&](const bf16 (&Hr)[2][136], bf16 (&Hw)[2][136], int s,
                  bf16x4 (&gU)[4], bf16x4 (&gF)[4]) {
    // B-operand: h(s-1); col c carries batch c&1
    bf16x8 hf[4];
    #pragma unroll
    for (int kk = 0; kk < 4; ++kk)
      hf[kk] = *(const bf16x8*)&Hr[b16 & 1][kk*32 + fg*8];

    // prefetch gx for s+2 (stays in flight across barrier)
    if (act) {
      int sf = (s + 2 < S_) ? s + 2 : 0;
      #pragma unroll
      for (int g = 0; g < 4; ++g)
        gF[g] = *(const bf16x4*)(gxp + (size_t)sf*512 + g*16);
    }

    // 16 MFMA (4 gates x 4 k-slices)
    f32x4 acc[4];
    #pragma unroll
    for (int g = 0; g < 4; ++g)
      acc[g] = __builtin_amdgcn_mfma_f32_16x16x32_bf16(rf[g][0], hf[0], zv, 0, 0, 0);
    #pragma unroll
    for (int kk = 1; kk < 4; ++kk)
      #pragma unroll
      for (int g = 0; g < 4; ++g)
        acc[g] = __builtin_amdgcn_mfma_f32_16x16x32_bf16(rf[g][kk], hf[kk], acc[g], 0, 0, 0);

    // pointwise directly in MFMA layout: 4 outputs per active lane
    if (act) {
      bf16x4 hb;
      #pragma unroll
      for (int jj = 0; jj < 4; ++jj) {
        float ir  = acc[0][jj] + (float)gU[0][jj];
        float fr_ = acc[1][jj] + (float)gU[1][jj];
        float zr  = acc[2][jj] + (float)gU[2][jj];
        float og  = acc[3][jj] + (float)gU[3][jj];
        float t   = __builtin_amdgcn_exp2f(-fr_);
        float lfm = mS[jj] - __builtin_amdgcn_logf(1.f + t);
        float d   = ir - lfm;
        float e   = __builtin_amdgcn_exp2f(-fabsf(d));
        float iG  = (d >= 0.f) ? 1.f : e;
        float fG  = (d >= 0.f) ? e : 1.f;
        mS[jj] = fmaxf(ir, lfm);
        float e2  = __builtin_amdgcn_exp2f(zr);
        float th  = 1.f - 2.f*__builtin_amdgcn_rcpf(e2 + 1.f);
        cS[jj] = fG*cS[jj] + iG*th;
        nS[jj] = fG*nS[jj] + iG;
        float eo  = __builtin_amdgcn_exp2f(-og);
        hv[jj] = cS[jj] * __builtin_amdgcn_rcpf(nS[jj] + nS[jj]*eo);
        hb[jj] = (bf16)hv[jj];
      }
      // h(s): one ds_write_b64 + one 8B global store
      *(bf16x4*)&Hw[b16][o0] = hb;
      *(bf16x4*)(hsp + (size_t)s*D_) = hb;
    }

    __builtin_amdgcn_sched_barrier(0);
    __builtin_amdgcn_s_waitcnt(0xC07F);   // lgkmcnt(0); vmcnt untouched
    __builtin_amdgcn_s_barrier();
    __builtin_amdgcn_sched_barrier(0);
  };

  for (int s = 0; s < S_; s += 4) {
    step(H[0], H[1], s,     ga[0], ga[2]);
    step(H[1], H[0], s + 1, ga[1], ga[3]);
    step(H[0], H[1], s + 2, ga[2], ga[0]);
    step(H[1], H[0], s + 3, ga[3], ga[1]);
  }

  if (act) {
    const float LN2 = 0.6931471805599453f;
    size_t sb = ((size_t)b*NH_ + n)*HD_ + o0;
    *(float4*)(stateOut +         sb) = make_float4(hv[0], hv[1], hv[2], hv[3]);
    *(float4*)(stateOut +  8192 + sb) = make_float4(cS[0], cS[1], cS[2], cS[3]);
    *(float4*)(stateOut + 16384 + sb) = make_float4(nS[0], nS[1], nS[2], nS[3]);
    *(float4*)(stateOut + 24576 + sb) = make_float4(mS[0]*LN2, mS[1]*LN2, mS[2]*LN2, mS[3]*LN2);
  }
}

// ---------------- fused groupnorm + residual + rmsnorm2 ----------------
// writes xr = x + y  into d_out (f32), and xn2 (bf16) for the FFN
__global__ __launch_bounds__(256) void fuse_gn_kernel(
    const bf16* __restrict__ hs, const float* __restrict__ x,
    const float* __restrict__ gnw, const float* __restrict__ r2w,
    float* __restrict__ xr, bf16* __restrict__ xn2)
{
  const int row = blockIdx.x, t = threadIdx.x;
  const size_t base = (size_t)row * D_;
  bf16x4 hraw = ((const bf16x4*)(hs + base))[t];
  float h0 = (float)hraw[0], h1 = (float)hraw[1], h2 = (float)hraw[2], h3 = (float)hraw[3];
  float4 xv = ((const float4*)(x + base))[t];
  float sum = h0 + h1 + h2 + h3;
  float sq  = h0*h0 + h1*h1 + h2*h2 + h3*h3;
  #pragma unroll
  for (int m = 1; m <= 16; m <<= 1) { sum += __shfl_xor(sum, m); sq += __shfl_xor(sq, m); }
  float mu = sum * (1.f/128.f);
  float var = sq * (1.f/128.f) - mu*mu;
  float rstd = rsqrtf(var + 1e-6f);
  float4 gw = ((const float4*)gnw)[t];
  float r0 = xv.x + (h0-mu)*rstd*gw.x;
  float r1 = xv.y + (h1-mu)*rstd*gw.y;
  float r2 = xv.z + (h2-mu)*rstd*gw.z;
  float r3 = xv.w + (h3-mu)*rstd*gw.w;
  ((float4*)(xr + base))[t] = make_float4(r0, r1, r2, r3);
  float p = r0*r0 + r1*r1 + r2*r2 + r3*r3;
  #pragma unroll
  for (int m = 1; m <= 32; m <<= 1) p += __shfl_xor(p, m);
  __shared__ float red[4];
  if ((t & 63) == 0) red[t >> 6] = p;
  __syncthreads();
  float rs = rsqrtf((red[0]+red[1]+red[2]+red[3]) * (1.f/1024.f) + 1e-6f);
  float4 w2 = ((const float4*)r2w)[t];
  bf16x4 o;
  o[0] = (bf16)(r0*rs*w2.x); o[1] = (bf16)(r1*rs*w2.y);
  o[2] = (bf16)(r2*rs*w2.z); o[3] = (bf16)(r3*rs*w2.w);
  ((bf16x4*)(xn2 + base))[t] = o;
}

extern "C" void kernel_launch(void* const* d_in, const int* in_sizes, int n_in,
                              void* d_out, int out_size, void* d_ws, size_t ws_size,
                              hipStream_t stream)
{
  const float* x     = (const float*)d_in[0];
  const float* rms1w = (const float*)d_in[1];
  const float* rms2w = (const float*)d_in[2];
  const float* Wg    = (const float*)d_in[3];
  const float* R     = (const float*)d_in[4];
  const float* bvec  = (const float*)d_in[5];
  const float* gnw   = (const float*)d_in[6];
  const float* Wgate = (const float*)d_in[7];
  const float* Wup   = (const float*)d_in[8];
  const float* Wdown = (const float*)d_in[9];
  float* out = (float*)d_out;
  float* stateOut = out + (size_t)ROWS * D_;

  char* ws = (char*)d_ws;
  size_t off = 0;
  auto alloc = [&](size_t bytes) -> void* {
    void* p = ws + off; off += (bytes + 255) & ~(size_t)255; return p;
  };
  // total ~210.5 MiB
  bf16*  xn     = (bf16*)alloc((size_t)ROWS * D_ * 2);          // 33.5MB (xn, later xn2)
  bf16*  hsbuf  = (bf16*)alloc((size_t)ROWS * D_ * 2);          // 33.5MB
  bf16*  bigbuf = (bf16*)alloc((size_t)NH_ * ROWS * 512 * 2);   // 134MB (gx, later gate/act 92MB)
  bf16*  Wgpk   = (bf16*)alloc(8*512*128*2);
  bf16*  Rpk    = (bf16*)alloc(8*512*128*2);
  float* biaspk = (float*)alloc(8*512*4);
  bf16*  Wgatepk = (bf16*)alloc((size_t)UPP * D_ * 2);
  bf16*  Wuppk   = (bf16*)alloc((size_t)UPP * D_ * 2);
  bf16*  Wdownpk = (bf16*)alloc((size_t)D_ * UPP * 2);

  pack_wgr_kernel<<<2048, 256, 0, stream>>>(Wg, R, bvec, Wgpk, Rpk, biaspk);
  packT_kernel<<<dim3(16, 44), 256, 0, stream>>>(Wgate, Wgatepk, 1024, 2816, 1024, 2752);
  packT_kernel<<<dim3(16, 44), 256, 0, stream>>>(Wup,   Wuppk,   1024, 2816, 1024, 2752);
  packT_kernel<<<dim3(44, 16), 256, 0, stream>>>(Wdown, Wdownpk, 2816, 1024, 2752, 1024);

  rmsnorm1_kernel<<<ROWS, 256, 0, stream>>>(x, rms1w, xn);

  // gx = blockdiag-per-head GEMM + bias (pre-scaled by log2e per gate)
  gemm_bt<0><<<dim3(4, 128, 8), 256, 0, stream>>>(xn, D_, Wgpk, 128,
      nullptr, bigbuf, 512, biaspk, nullptr, nullptr, 128);

  recur_kernel<<<32, 512, 0, stream>>>(bigbuf, Rpk, hsbuf, stateOut);

  // xr -> d_out, xn2 -> xn
  fuse_gn_kernel<<<ROWS, 256, 0, stream>>>(hsbuf, x, gnw, rms2w, out, xn);

  bf16* gate = bigbuf;  // gx dead; reuse as gate/act [ROWS][2816]
  gemm_bt<1><<<dim3(22, 128), 256, 0, stream>>>(xn, D_, Wgatepk, D_,
      nullptr, gate, UPP, nullptr, nullptr, nullptr, D_);
  // up GEMM with fused silu(gate)*up, in-place into gate
  gemm_bt<3><<<dim3(22, 128), 256, 0, stream>>>(xn, D_, Wuppk, D_,
      nullptr, gate, UPP, nullptr, nullptr, gate, D_);

  // out = xr + act @ Wdown^T   (residual read from d_out, written in place)
  gemm_bt<2><<<dim3(8, 128), 256, 0, stream>>>(gate, UPP, Wdownpk, UPP,
      out, nullptr, D_, nullptr, out, nullptr, UPP);
}

// Round 9
// 2075.230 us; speedup vs baseline: 2.1256x; 2.1256x over previous
//
#include <hip/hip_runtime.h>

typedef __bf16 bf16;
typedef bf16 bf16x8 __attribute__((ext_vector_type(8)));
typedef bf16 bf16x4 __attribute__((ext_vector_type(4)));
typedef float f32x4 __attribute__((ext_vector_type(4)));

#define B_ 8
#define S_ 2048
#define D_ 1024
#define NH_ 8
#define HD_ 128
#define UPP 2816
#define ROWS (B_*S_)

__device__ __forceinline__ void gload_lds16(const void* gsrc, void* ldsdst) {
  __builtin_amdgcn_global_load_lds(
      (const __attribute__((address_space(1))) void*)gsrc,
      (__attribute__((address_space(3))) void*)ldsdst, 16, 0, 0);
}

// ---------------- weight packing ----------------
// Wg/R: [4][NH][HD][HD] -> per-head [512][128] bf16 with col j=(o>>4)*64+g*16+(o&15)
// Pre-scaled by log2(e) per gate (2*log2(e) for z): recurrence in exp2/log2 domain.
__global__ __launch_bounds__(256) void pack_wgr_kernel(
    const float* __restrict__ Wg, const float* __restrict__ R, const float* __restrict__ bv,
    bf16* __restrict__ Wgpk, bf16* __restrict__ Rpk, float* __restrict__ biaspk)
{
  const float K2 = 1.442695040888963f;
  int idx = blockIdx.x * 256 + threadIdx.x;
  if (idx < 8*512*128) {
    int k = idx & 127, j = (idx >> 7) & 511, n = idx >> 16;
    int g = (j >> 4) & 3, o = ((j >> 6) << 4) | (j & 15);
    float sc = (g == 2) ? 2.f*K2 : K2;
    size_t src = (((size_t)(g*8 + n)*128 + o)*128 + k);
    Wgpk[idx] = (bf16)(Wg[src] * sc);
    Rpk[idx]  = (bf16)(R[src] * sc);
  }
  if (idx < 8*512) {
    int j = idx & 511, n = idx >> 9;
    int g = (j >> 4) & 3, o = ((j >> 6) << 4) | (j & 15);
    float sc = (g == 2) ? 2.f*K2 : K2;
    biaspk[idx] = bv[g*1024 + n*128 + o] * sc;
  }
}

// out[j][k] = (k<K_in && j<N_in) ? in[k][j] : 0 ;  out dims [N_out][K_out]
__global__ __launch_bounds__(256) void packT_kernel(
    const float* __restrict__ in, bf16* __restrict__ out,
    int K_out, int N_out, int K_in, int N_in)
{
  __shared__ float tile[64][65];
  int k0 = blockIdx.x * 64, j0 = blockIdx.y * 64;
  int tj = threadIdx.x & 63, t4 = threadIdx.x >> 6;
  #pragma unroll
  for (int p = 0; p < 16; ++p) {
    int kk = p*4 + t4, k = k0 + kk, j = j0 + tj;
    tile[kk][tj] = (k < K_in && j < N_in) ? in[(size_t)k * N_in + j] : 0.f;
  }
  __syncthreads();
  #pragma unroll
  for (int p = 0; p < 16; ++p) {
    int jj = p*4 + t4, j = j0 + jj, k = k0 + tj;
    if (j < N_out && k < K_out) out[(size_t)j * K_out + k] = (bf16)tile[tj][jj];
  }
}

// ---------------- rmsnorm1: x -> xn (bf16) ----------------
__global__ __launch_bounds__(256) void rmsnorm1_kernel(
    const float* __restrict__ x, const float* __restrict__ w, bf16* __restrict__ xn)
{
  const int row = blockIdx.x, t = threadIdx.x;
  const size_t base = (size_t)row * D_;
  float4 xv = ((const float4*)(x + base))[t];
  float p = xv.x*xv.x + xv.y*xv.y + xv.z*xv.z + xv.w*xv.w;
  #pragma unroll
  for (int m = 1; m <= 32; m <<= 1) p += __shfl_xor(p, m);
  __shared__ float red[4];
  if ((t & 63) == 0) red[t >> 6] = p;
  __syncthreads();
  float rs = rsqrtf((red[0]+red[1]+red[2]+red[3]) * (1.f/1024.f) + 1e-6f);
  float4 wv = ((const float4*)w)[t];
  bf16x4 o;
  o[0] = (bf16)(xv.x*rs*wv.x); o[1] = (bf16)(xv.y*rs*wv.y);
  o[2] = (bf16)(xv.z*rs*wv.z); o[3] = (bf16)(xv.w*rs*wv.w);
  ((bf16x4*)(xn + base))[t] = o;
}

// ---------------- GEMM: C[M,N] = A[M,K] * B[N,K]^T  (both bf16, row-major) ----------------
#define BM 128
#define BN 128
#define BKK 64
// MODE 0: gx (per-head via blockIdx.z, bf16 out + bias)
// MODE 2: f32 out + residual (res may alias Cf)
template<int MODE>
__global__ __launch_bounds__(256) void gemm_bt(
    const bf16* __restrict__ A, int lda,
    const bf16* __restrict__ B, int ldb,
    float* Cf, bf16* Cb, int ldc,
    const float* __restrict__ bias, const float* res, int K)
{
  __shared__ __align__(16) bf16 As[BM*BKK];
  __shared__ __align__(16) bf16 Bs[BN*BKK];
  if constexpr (MODE == 0) {
    const int h = blockIdx.z;
    A += h * HD_;
    B += (size_t)h * (512*128);
    Cb += (size_t)h * ((size_t)ROWS * 512);
    bias += h * 512;
  }
  const int tid = threadIdx.x;
  const int lane = tid & 63, wave = tid >> 6;
  const int row0 = blockIdx.y * BM, col0 = blockIdx.x * BN;
  const int srow = lane >> 3, scol = (lane & 7) * 8;
  const int wr = (wave >> 1) * 64, wc = (wave & 1) * 64;
  const int fr = lane & 15, fg = lane >> 4;
  f32x4 acc[4][4] = {};

  for (int k0 = 0; k0 < K; k0 += BKK) {
    __syncthreads();
    #pragma unroll
    for (int c = 0; c < 4; ++c) {
      const int slot = wave * 4 + c;
      const int r = slot * 8 + srow;
      gload_lds16(A + (size_t)(row0 + r) * lda + (k0 + scol), &As[slot * 512]);
      gload_lds16(B + (size_t)(col0 + r) * ldb + (k0 + scol), &Bs[slot * 512]);
    }
    __syncthreads();
    #pragma unroll
    for (int kk = 0; kk < 2; ++kk) {
      bf16x8 af[4], bfv[4];
      #pragma unroll
      for (int m = 0; m < 4; ++m)
        af[m] = *(const bf16x8*)&As[(wr + m*16 + fr)*BKK + kk*32 + fg*8];
      #pragma unroll
      for (int nn = 0; nn < 4; ++nn)
        bfv[nn] = *(const bf16x8*)&Bs[(wc + nn*16 + fr)*BKK + kk*32 + fg*8];
      #pragma unroll
      for (int m = 0; m < 4; ++m)
        #pragma unroll
        for (int nn = 0; nn < 4; ++nn)
          acc[m][nn] = __builtin_amdgcn_mfma_f32_16x16x32_bf16(af[m], bfv[nn], acc[m][nn], 0, 0, 0);
    }
  }

  #pragma unroll
  for (int m = 0; m < 4; ++m) {
    const int rbase = row0 + wr + m*16 + fg*4;
    #pragma unroll
    for (int nn = 0; nn < 4; ++nn) {
      const int col = col0 + wc + nn*16 + fr;
      #pragma unroll
      for (int j = 0; j < 4; ++j) {
        const size_t off = (size_t)(rbase + j) * ldc + col;
        float v = acc[m][nn][j];
        if constexpr (MODE == 0) Cb[off] = (bf16)(v + bias[col]);
        if constexpr (MODE == 2) Cf[off] = v + res[off];
      }
    }
  }
}

// ---------------- fused gate+up GEMM with silu epilogue ----------------
// act[M,N] = silu(A@Bg^T) * (A@Bu^T).  A staged once for both products.
__global__ __launch_bounds__(256) void gemm_gateup(
    const bf16* __restrict__ A,
    const bf16* __restrict__ Bg, const bf16* __restrict__ Bu,
    bf16* __restrict__ act)
{
  __shared__ __align__(16) bf16 As[BM*BKK];
  __shared__ __align__(16) bf16 Bgs[BN*BKK];
  __shared__ __align__(16) bf16 Bus[BN*BKK];
  const int tid = threadIdx.x;
  const int lane = tid & 63, wave = tid >> 6;
  const int row0 = blockIdx.y * BM, col0 = blockIdx.x * BN;
  const int srow = lane >> 3, scol = (lane & 7) * 8;
  const int wr = (wave >> 1) * 64, wc = (wave & 1) * 64;
  const int fr = lane & 15, fg = lane >> 4;
  f32x4 accg[4][4] = {}, accu[4][4] = {};

  for (int k0 = 0; k0 < D_; k0 += BKK) {
    __syncthreads();
    #pragma unroll
    for (int c = 0; c < 4; ++c) {
      const int slot = wave * 4 + c;
      const int r = slot * 8 + srow;
      gload_lds16(A  + (size_t)(row0 + r) * D_ + (k0 + scol), &As[slot * 512]);
      gload_lds16(Bg + (size_t)(col0 + r) * D_ + (k0 + scol), &Bgs[slot * 512]);
      gload_lds16(Bu + (size_t)(col0 + r) * D_ + (k0 + scol), &Bus[slot * 512]);
    }
    __syncthreads();
    #pragma unroll
    for (int kk = 0; kk < 2; ++kk) {
      bf16x8 af[4], bg[4], bu[4];
      #pragma unroll
      for (int m = 0; m < 4; ++m)
        af[m] = *(const bf16x8*)&As[(wr + m*16 + fr)*BKK + kk*32 + fg*8];
      #pragma unroll
      for (int nn = 0; nn < 4; ++nn) {
        bg[nn] = *(const bf16x8*)&Bgs[(wc + nn*16 + fr)*BKK + kk*32 + fg*8];
        bu[nn] = *(const bf16x8*)&Bus[(wc + nn*16 + fr)*BKK + kk*32 + fg*8];
      }
      #pragma unroll
      for (int m = 0; m < 4; ++m)
        #pragma unroll
        for (int nn = 0; nn < 4; ++nn) {
          accg[m][nn] = __builtin_amdgcn_mfma_f32_16x16x32_bf16(af[m], bg[nn], accg[m][nn], 0, 0, 0);
          accu[m][nn] = __builtin_amdgcn_mfma_f32_16x16x32_bf16(af[m], bu[nn], accu[m][nn], 0, 0, 0);
        }
    }
  }

  #pragma unroll
  for (int m = 0; m < 4; ++m) {
    const int rbase = row0 + wr + m*16 + fg*4;
    #pragma unroll
    for (int nn = 0; nn < 4; ++nn) {
      const int col = col0 + wc + nn*16 + fr;
      #pragma unroll
      for (int j = 0; j < 4; ++j) {
        float gf = accg[m][nn][j], uf = accu[m][nn][j];
        act[(size_t)(rbase + j) * UPP + col] = (bf16)(gf / (1.f + __expf(-gf)) * uf);
      }
    }
  }
}

// ---------------- sLSTM recurrence: 32 blocks = (head, batch-pair), 4 waves ----------------
// (R6 structure — empirical best. scr padded [8][16]->[8][17] to break the 4-way
// bank conflict on the b32 redistribution read; write side stays conflict-free.)
__global__ __launch_bounds__(256, 1) void recur_kernel(
    const bf16* __restrict__ gx, const bf16* __restrict__ Rpk,
    bf16* __restrict__ hs, float* __restrict__ stateOut)
{
  const int n  = blockIdx.x >> 2;       // head
  const int bp = blockIdx.x & 3;        // batch pair
  const int tid = threadIdx.x, w = tid >> 6, l = tid & 63;
  const int b16 = l & 15, fg = l >> 4;
  const int bl  = l & 1;                // local batch (0/1)
  const int r   = l >> 1;               // o within wave's 32-block
  const int q   = r >> 4, r16 = r & 15;
  const int b   = bp*2 + bl;            // global batch
  const int o   = w*32 + r;             // head-local output index [0,128)

  __shared__ __align__(16) bf16 H[2][2][136];        // [buf][bl][o]
  __shared__ __align__(16) float scr[4][2][8][17];   // [wave][bl][tt][r16] padded
  for (int i = tid; i < 2*2*136; i += 256) ((bf16*)H)[i] = (bf16)0.f;
  __syncthreads();

  // R fragments, register-resident: 8 tiles x 4 k-slices (128 VGPR)
  bf16x8 rf[8][4];
  #pragma unroll
  for (int tt = 0; tt < 8; ++tt)
    #pragma unroll
    for (int kk = 0; kk < 4; ++kk)
      rf[tt][kk] = *(const bf16x8*)&Rpk[(size_t)n*65536 + (size_t)(w*128 + tt*16 + b16)*128 + kk*32 + fg*8];

  // pinned zero accumulator source
  f32x4 zv = {0.f, 0.f, 0.f, 0.f};
  asm volatile("" : "+v"(zv));

  float cS = 0.f, nS = 0.f, mS = 0.f, hv = 0.f;

  // gx element base: j(g) = (w*2+q)*64 + g*16 + r16 ; per-step advance = 512 elems
  const bf16* gxp = gx + (size_t)n * ROWS * 512 + (size_t)b * S_ * 512
                    + (size_t)(w*2 + q) * 64 + r16;
  bf16* hsp = hs + (size_t)b * S_ * D_ + n * HD_ + o;

  bf16 ga[4][4];   // rotating gate-preact buffers [slot][g]
  #pragma unroll
  for (int g = 0; g < 4; ++g) {
    ga[0][g] = gxp[(size_t)0*512 + g*16];
    ga[1][g] = gxp[(size_t)1*512 + g*16];
  }

  auto step = [&](const bf16 (&Hr)[2][136], bf16 (&Hw)[2][136], int s,
                  bf16 (&gU)[4], bf16 (&gF)[4]) {
    // B-operand: h(s-1); cols 0/1 = batches, cols 2-15 duplicate (don't care)
    bf16x8 hf[4];
    #pragma unroll
    for (int kk = 0; kk < 4; ++kk)
      hf[kk] = *(const bf16x8*)&Hr[b16 & 1][kk*32 + fg*8];

    // prefetch gx for s+2
    {
      int sf = (s + 2 < S_) ? s + 2 : 0;
      #pragma unroll
      for (int g = 0; g < 4; ++g)
        gF[g] = gxp[(size_t)sf*512 + g*16];
    }

    // 32 MFMA
    f32x4 acc[8];
    #pragma unroll
    for (int tt = 0; tt < 8; ++tt)
      acc[tt] = __builtin_amdgcn_mfma_f32_16x16x32_bf16(rf[tt][0], hf[0], zv, 0, 0, 0);
    #pragma unroll
    for (int kk = 1; kk < 4; ++kk)
      #pragma unroll
      for (int tt = 0; tt < 8; ++tt)
        acc[tt] = __builtin_amdgcn_mfma_f32_16x16x32_bf16(rf[tt][kk], hf[kk], acc[tt], 0, 0, 0);

    // redistribute via padded per-wave scratch: 8 ds_write_b128 + 4 ds_read_b32
    if (b16 < 2) {
      #pragma unroll
      for (int tt = 0; tt < 8; ++tt)
        *(f32x4*)&scr[w][b16][tt][fg*4] = acc[tt];
    }
    float pre[4];
    #pragma unroll
    for (int g = 0; g < 4; ++g)
      pre[g] = scr[w][bl][q*4 + g][r16];

    // pointwise, log2 domain — ONE output per lane
    float ir  = pre[0] + (float)gU[0];
    float fr_ = pre[1] + (float)gU[1];
    float zr  = pre[2] + (float)gU[2];
    float og  = pre[3] + (float)gU[3];
    float t   = __builtin_amdgcn_exp2f(-fr_);
    float lfm = mS - __builtin_amdgcn_logf(1.f + t);
    float d   = ir - lfm;
    float e   = __builtin_amdgcn_exp2f(-fabsf(d));
    float iG  = (d >= 0.f) ? 1.f : e;
    float fG  = (d >= 0.f) ? e : 1.f;
    mS = fmaxf(ir, lfm);
    float e2  = __builtin_amdgcn_exp2f(zr);
    float th  = 1.f - 2.f*__builtin_amdgcn_rcpf(e2 + 1.f);
    cS = fG*cS + iG*th;
    nS = fG*nS + iG;
    float eo  = __builtin_amdgcn_exp2f(-og);
    hv = cS * __builtin_amdgcn_rcpf(nS + nS*eo);

    // write h(s): LDS (other buffer) + global stream (never waited on)
    bf16 hb = (bf16)hv;
    Hw[bl][o] = hb;
    hsp[(size_t)s*D_] = hb;

    __builtin_amdgcn_sched_barrier(0);
    __builtin_amdgcn_s_waitcnt(0xC07F);   // lgkmcnt(0); vmcnt untouched
    __builtin_amdgcn_s_barrier();
    __builtin_amdgcn_sched_barrier(0);
  };

  for (int s = 0; s < S_; s += 4) {
    step(H[0], H[1], s,     ga[0], ga[2]);
    step(H[1], H[0], s + 1, ga[1], ga[3]);
    step(H[0], H[1], s + 2, ga[2], ga[0]);
    step(H[1], H[0], s + 3, ga[3], ga[1]);
  }

  {
    const float LN2 = 0.6931471805599453f;
    size_t sb = ((size_t)b*NH_ + n)*HD_ + o;
    stateOut[sb]         = hv;
    stateOut[8192  + sb] = cS;
    stateOut[16384 + sb] = nS;
    stateOut[24576 + sb] = mS * LN2;
  }
}

// ---------------- fused groupnorm + residual + rmsnorm2 ----------------
// writes xr = x + y  into d_out (f32), and xn2 (bf16) for the FFN
__global__ __launch_bounds__(256) void fuse_gn_kernel(
    const bf16* __restrict__ hs, const float* __restrict__ x,
    const float* __restrict__ gnw, const float* __restrict__ r2w,
    float* __restrict__ xr, bf16* __restrict__ xn2)
{
  const int row = blockIdx.x, t = threadIdx.x;
  const size_t base = (size_t)row * D_;
  bf16x4 hraw = ((const bf16x4*)(hs + base))[t];
  float h0 = (float)hraw[0], h1 = (float)hraw[1], h2 = (float)hraw[2], h3 = (float)hraw[3];
  float4 xv = ((const float4*)(x + base))[t];
  float sum = h0 + h1 + h2 + h3;
  float sq  = h0*h0 + h1*h1 + h2*h2 + h3*h3;
  #pragma unroll
  for (int m = 1; m <= 16; m <<= 1) { sum += __shfl_xor(sum, m); sq += __shfl_xor(sq, m); }
  float mu = sum * (1.f/128.f);
  float var = sq * (1.f/128.f) - mu*mu;
  float rstd = rsqrtf(var + 1e-6f);
  float4 gw = ((const float4*)gnw)[t];
  float r0 = xv.x + (h0-mu)*rstd*gw.x;
  float r1 = xv.y + (h1-mu)*rstd*gw.y;
  float r2 = xv.z + (h2-mu)*rstd*gw.z;
  float r3 = xv.w + (h3-mu)*rstd*gw.w;
  ((float4*)(xr + base))[t] = make_float4(r0, r1, r2, r3);
  float p = r0*r0 + r1*r1 + r2*r2 + r3*r3;
  #pragma unroll
  for (int m = 1; m <= 32; m <<= 1) p += __shfl_xor(p, m);
  __shared__ float red[4];
  if ((t & 63) == 0) red[t >> 6] = p;
  __syncthreads();
  float rs = rsqrtf((red[0]+red[1]+red[2]+red[3]) * (1.f/1024.f) + 1e-6f);
  float4 w2 = ((const float4*)r2w)[t];
  bf16x4 o;
  o[0] = (bf16)(r0*rs*w2.x); o[1] = (bf16)(r1*rs*w2.y);
  o[2] = (bf16)(r2*rs*w2.z); o[3] = (bf16)(r3*rs*w2.w);
  ((bf16x4*)(xn2 + base))[t] = o;
}

extern "C" void kernel_launch(void* const* d_in, const int* in_sizes, int n_in,
                              void* d_out, int out_size, void* d_ws, size_t ws_size,
                              hipStream_t stream)
{
  const float* x     = (const float*)d_in[0];
  const float* rms1w = (const float*)d_in[1];
  const float* rms2w = (const float*)d_in[2];
  const float* Wg    = (const float*)d_in[3];
  const float* R     = (const float*)d_in[4];
  const float* bvec  = (const float*)d_in[5];
  const float* gnw   = (const float*)d_in[6];
  const float* Wgate = (const float*)d_in[7];
  const float* Wup   = (const float*)d_in[8];
  const float* Wdown = (const float*)d_in[9];
  float* out = (float*)d_out;
  float* stateOut = out + (size_t)ROWS * D_;

  char* ws = (char*)d_ws;
  size_t off = 0;
  auto alloc = [&](size_t bytes) -> void* {
    void* p = ws + off; off += (bytes + 255) & ~(size_t)255; return p;
  };
  // total ~210.5 MiB
  bf16*  xn     = (bf16*)alloc((size_t)ROWS * D_ * 2);          // 33.5MB (xn, later xn2)
  bf16*  hsbuf  = (bf16*)alloc((size_t)ROWS * D_ * 2);          // 33.5MB
  bf16*  bigbuf = (bf16*)alloc((size_t)NH_ * ROWS * 512 * 2);   // 134MB (gx, later act 92MB)
  bf16*  Wgpk   = (bf16*)alloc(8*512*128*2);
  bf16*  Rpk    = (bf16*)alloc(8*512*128*2);
  float* biaspk = (float*)alloc(8*512*4);
  bf16*  Wgatepk = (bf16*)alloc((size_t)UPP * D_ * 2);
  bf16*  Wuppk   = (bf16*)alloc((size_t)UPP * D_ * 2);
  bf16*  Wdownpk = (bf16*)alloc((size_t)D_ * UPP * 2);

  pack_wgr_kernel<<<2048, 256, 0, stream>>>(Wg, R, bvec, Wgpk, Rpk, biaspk);
  packT_kernel<<<dim3(16, 44), 256, 0, stream>>>(Wgate, Wgatepk, 1024, 2816, 1024, 2752);
  packT_kernel<<<dim3(16, 44), 256, 0, stream>>>(Wup,   Wuppk,   1024, 2816, 1024, 2752);
  packT_kernel<<<dim3(44, 16), 256, 0, stream>>>(Wdown, Wdownpk, 2816, 1024, 2752, 1024);

  rmsnorm1_kernel<<<ROWS, 256, 0, stream>>>(x, rms1w, xn);

  // gx = blockdiag-per-head GEMM + bias (pre-scaled by log2e per gate)
  gemm_bt<0><<<dim3(4, 128, 8), 256, 0, stream>>>(xn, D_, Wgpk, 128,
      nullptr, bigbuf, 512, biaspk, nullptr, 128);

  recur_kernel<<<32, 256, 0, stream>>>(bigbuf, Rpk, hsbuf, stateOut);

  // xr -> d_out, xn2 -> xn
  fuse_gn_kernel<<<ROWS, 256, 0, stream>>>(hsbuf, x, gnw, rms2w, out, xn);

  // act = silu(xn@Wg^T) * (xn@Wu^T), written into bigbuf (gx dead)
  bf16* act = bigbuf;
  gemm_gateup<<<dim3(22, 128), 256, 0, stream>>>(xn, Wgatepk, Wuppk, act);

  // out = xr + act @ Wdown^T   (residual read from d_out, written in place)
  gemm_bt<2><<<dim3(8, 128), 256, 0, stream>>>(act, UPP, Wdownpk, UPP,
      out, nullptr, D_, nullptr, out, UPP);
}

// Round 10
// 1966.141 us; speedup vs baseline: 2.2436x; 1.0555x over previous
//
#include <hip/hip_runtime.h>

typedef __bf16 bf16;
typedef bf16 bf16x8 __attribute__((ext_vector_type(8)));
typedef bf16 bf16x4 __attribute__((ext_vector_type(4)));
typedef float f32x4 __attribute__((ext_vector_type(4)));

#define B_ 8
#define S_ 2048
#define D_ 1024
#define NH_ 8
#define HD_ 128
#define UPP 2816
#define ROWS (B_*S_)

__device__ __forceinline__ void gload_lds16(const void* gsrc, void* ldsdst) {
  __builtin_amdgcn_global_load_lds(
      (const __attribute__((address_space(1))) void*)gsrc,
      (__attribute__((address_space(3))) void*)ldsdst, 16, 0, 0);
}

// ---------------- weight packing ----------------
// Wg/R: [4][NH][HD][HD] -> per-head [512][128] bf16 with col j=(o>>4)*64+g*16+(o&15)
// Pre-scaled by log2(e) per gate (2*log2(e) for z): recurrence in exp2/log2 domain.
__global__ __launch_bounds__(256) void pack_wgr_kernel(
    const float* __restrict__ Wg, const float* __restrict__ R, const float* __restrict__ bv,
    bf16* __restrict__ Wgpk, bf16* __restrict__ Rpk, float* __restrict__ biaspk)
{
  const float K2 = 1.442695040888963f;
  int idx = blockIdx.x * 256 + threadIdx.x;
  if (idx < 8*512*128) {
    int k = idx & 127, j = (idx >> 7) & 511, n = idx >> 16;
    int g = (j >> 4) & 3, o = ((j >> 6) << 4) | (j & 15);
    float sc = (g == 2) ? 2.f*K2 : K2;
    size_t src = (((size_t)(g*8 + n)*128 + o)*128 + k);
    Wgpk[idx] = (bf16)(Wg[src] * sc);
    Rpk[idx]  = (bf16)(R[src] * sc);
  }
  if (idx < 8*512) {
    int j = idx & 511, n = idx >> 9;
    int g = (j >> 4) & 3, o = ((j >> 6) << 4) | (j & 15);
    float sc = (g == 2) ? 2.f*K2 : K2;
    biaspk[idx] = bv[g*1024 + n*128 + o] * sc;
  }
}

// out[j][k] = (k<K_in && j<N_in) ? in[k][j] : 0 ;  out dims [N_out][K_out]
__global__ __launch_bounds__(256) void packT_kernel(
    const float* __restrict__ in, bf16* __restrict__ out,
    int K_out, int N_out, int K_in, int N_in)
{
  __shared__ float tile[64][65];
  int k0 = blockIdx.x * 64, j0 = blockIdx.y * 64;
  int tj = threadIdx.x & 63, t4 = threadIdx.x >> 6;
  #pragma unroll
  for (int p = 0; p < 16; ++p) {
    int kk = p*4 + t4, k = k0 + kk, j = j0 + tj;
    tile[kk][tj] = (k < K_in && j < N_in) ? in[(size_t)k * N_in + j] : 0.f;
  }
  __syncthreads();
  #pragma unroll
  for (int p = 0; p < 16; ++p) {
    int jj = p*4 + t4, j = j0 + jj, k = k0 + tj;
    if (j < N_out && k < K_out) out[(size_t)j * K_out + k] = (bf16)tile[tj][jj];
  }
}

// ---------------- rmsnorm1: x -> xn (bf16) ----------------
__global__ __launch_bounds__(256) void rmsnorm1_kernel(
    const float* __restrict__ x, const float* __restrict__ w, bf16* __restrict__ xn)
{
  const int row = blockIdx.x, t = threadIdx.x;
  const size_t base = (size_t)row * D_;
  float4 xv = ((const float4*)(x + base))[t];
  float p = xv.x*xv.x + xv.y*xv.y + xv.z*xv.z + xv.w*xv.w;
  #pragma unroll
  for (int m = 1; m <= 32; m <<= 1) p += __shfl_xor(p, m);
  __shared__ float red[4];
  if ((t & 63) == 0) red[t >> 6] = p;
  __syncthreads();
  float rs = rsqrtf((red[0]+red[1]+red[2]+red[3]) * (1.f/1024.f) + 1e-6f);
  float4 wv = ((const float4*)w)[t];
  bf16x4 o;
  o[0] = (bf16)(xv.x*rs*wv.x); o[1] = (bf16)(xv.y*rs*wv.y);
  o[2] = (bf16)(xv.z*rs*wv.z); o[3] = (bf16)(xv.w*rs*wv.w);
  ((bf16x4*)(xn + base))[t] = o;
}

// ---------------- GEMM: C[M,N] = A[M,K] * B[N,K]^T  (both bf16, row-major) ----------------
#define BM 128
#define BN 128
#define BKK 64
// MODE 0: gx (per-head via blockIdx.z, bf16 out + bias)
// MODE 2: f32 out + residual (res may alias Cf); XCD-swizzled block index
template<int MODE>
__global__ __launch_bounds__(256) void gemm_bt(
    const bf16* __restrict__ A, int lda,
    const bf16* __restrict__ B, int ldb,
    float* Cf, bf16* Cb, int ldc,
    const float* __restrict__ bias, const float* res, int K)
{
  __shared__ __align__(16) bf16 As[BM*BKK];
  __shared__ __align__(16) bf16 Bs[BN*BKK];
  int bx = blockIdx.x, by = blockIdx.y;
  if constexpr (MODE == 0) {
    const int h = blockIdx.z;
    A += h * HD_;
    B += (size_t)h * (512*128);
    Cb += (size_t)h * ((size_t)ROWS * 512);
    bias += h * 512;
  }
  if constexpr (MODE == 2) {
    // T1: XCD-aware bijective swizzle (nwg % 8 == 0)
    const int gx_ = gridDim.x, nwg = gx_ * gridDim.y;
    const int wg = by * gx_ + bx;
    const int swz = (wg & 7) * (nwg >> 3) + (wg >> 3);
    bx = swz % gx_; by = swz / gx_;
  }
  const int tid = threadIdx.x;
  const int lane = tid & 63, wave = tid >> 6;
  const int row0 = by * BM, col0 = bx * BN;
  const int srow = lane >> 3, scol = (lane & 7) * 8;
  const int wr = (wave >> 1) * 64, wc = (wave & 1) * 64;
  const int fr = lane & 15, fg = lane >> 4;
  f32x4 acc[4][4] = {};

  for (int k0 = 0; k0 < K; k0 += BKK) {
    __syncthreads();
    #pragma unroll
    for (int c = 0; c < 4; ++c) {
      const int slot = wave * 4 + c;
      const int r = slot * 8 + srow;
      gload_lds16(A + (size_t)(row0 + r) * lda + (k0 + scol), &As[slot * 512]);
      gload_lds16(B + (size_t)(col0 + r) * ldb + (k0 + scol), &Bs[slot * 512]);
    }
    __syncthreads();
    #pragma unroll
    for (int kk = 0; kk < 2; ++kk) {
      bf16x8 af[4], bfv[4];
      #pragma unroll
      for (int m = 0; m < 4; ++m)
        af[m] = *(const bf16x8*)&As[(wr + m*16 + fr)*BKK + kk*32 + fg*8];
      #pragma unroll
      for (int nn = 0; nn < 4; ++nn)
        bfv[nn] = *(const bf16x8*)&Bs[(wc + nn*16 + fr)*BKK + kk*32 + fg*8];
      #pragma unroll
      for (int m = 0; m < 4; ++m)
        #pragma unroll
        for (int nn = 0; nn < 4; ++nn)
          acc[m][nn] = __builtin_amdgcn_mfma_f32_16x16x32_bf16(af[m], bfv[nn], acc[m][nn], 0, 0, 0);
    }
  }

  #pragma unroll
  for (int m = 0; m < 4; ++m) {
    const int rbase = row0 + wr + m*16 + fg*4;
    #pragma unroll
    for (int nn = 0; nn < 4; ++nn) {
      const int col = col0 + wc + nn*16 + fr;
      #pragma unroll
      for (int j = 0; j < 4; ++j) {
        const size_t off = (size_t)(rbase + j) * ldc + col;
        float v = acc[m][nn][j];
        if constexpr (MODE == 0) Cb[off] = (bf16)(v + bias[col]);
        if constexpr (MODE == 2) Cf[off] = v + res[off];
      }
    }
  }
}

// ---------------- fused gate+up GEMM with silu epilogue ----------------
// act[M,N] = silu(A@Bg^T) * (A@Bu^T).  A staged once for both products.
// T1 XCD swizzle on block index (nwg = 22*128 = 2816, % 8 == 0).
__global__ __launch_bounds__(256) void gemm_gateup(
    const bf16* __restrict__ A,
    const bf16* __restrict__ Bg, const bf16* __restrict__ Bu,
    bf16* __restrict__ act)
{
  __shared__ __align__(16) bf16 As[BM*BKK];
  __shared__ __align__(16) bf16 Bgs[BN*BKK];
  __shared__ __align__(16) bf16 Bus[BN*BKK];
  const int gx_ = gridDim.x, nwg = gx_ * gridDim.y;
  const int wg = blockIdx.y * gx_ + blockIdx.x;
  const int swz = (wg & 7) * (nwg >> 3) + (wg >> 3);
  const int bx = swz % gx_, by = swz / gx_;
  const int tid = threadIdx.x;
  const int lane = tid & 63, wave = tid >> 6;
  const int row0 = by * BM, col0 = bx * BN;
  const int srow = lane >> 3, scol = (lane & 7) * 8;
  const int wr = (wave >> 1) * 64, wc = (wave & 1) * 64;
  const int fr = lane & 15, fg = lane >> 4;
  f32x4 accg[4][4] = {}, accu[4][4] = {};

  for (int k0 = 0; k0 < D_; k0 += BKK) {
    __syncthreads();
    #pragma unroll
    for (int c = 0; c < 4; ++c) {
      const int slot = wave * 4 + c;
      const int r = slot * 8 + srow;
      gload_lds16(A  + (size_t)(row0 + r) * D_ + (k0 + scol), &As[slot * 512]);
      gload_lds16(Bg + (size_t)(col0 + r) * D_ + (k0 + scol), &Bgs[slot * 512]);
      gload_lds16(Bu + (size_t)(col0 + r) * D_ + (k0 + scol), &Bus[slot * 512]);
    }
    __syncthreads();
    #pragma unroll
    for (int kk = 0; kk < 2; ++kk) {
      bf16x8 af[4], bg[4], bu[4];
      #pragma unroll
      for (int m = 0; m < 4; ++m)
        af[m] = *(const bf16x8*)&As[(wr + m*16 + fr)*BKK + kk*32 + fg*8];
      #pragma unroll
      for (int nn = 0; nn < 4; ++nn) {
        bg[nn] = *(const bf16x8*)&Bgs[(wc + nn*16 + fr)*BKK + kk*32 + fg*8];
        bu[nn] = *(const bf16x8*)&Bus[(wc + nn*16 + fr)*BKK + kk*32 + fg*8];
      }
      #pragma unroll
      for (int m = 0; m < 4; ++m)
        #pragma unroll
        for (int nn = 0; nn < 4; ++nn) {
          accg[m][nn] = __builtin_amdgcn_mfma_f32_16x16x32_bf16(af[m], bg[nn], accg[m][nn], 0, 0, 0);
          accu[m][nn] = __builtin_amdgcn_mfma_f32_16x16x32_bf16(af[m], bu[nn], accu[m][nn], 0, 0, 0);
        }
    }
  }

  #pragma unroll
  for (int m = 0; m < 4; ++m) {
    const int rbase = row0 + wr + m*16 + fg*4;
    #pragma unroll
    for (int nn = 0; nn < 4; ++nn) {
      const int col = col0 + wc + nn*16 + fr;
      #pragma unroll
      for (int j = 0; j < 4; ++j) {
        float gf = accg[m][nn][j], uf = accu[m][nn][j];
        act[(size_t)(rbase + j) * UPP + col] = (bf16)(gf / (1.f + __expf(-gf)) * uf);
      }
    }
  }
}

// ---------------- sLSTM recurrence: 32 blocks = (head, batch-pair), 4 waves ----------------
// EXACT R6 structure (empirical best, 1265 us). scr UNPADDED [8][16]: R9 proved the
// 4-way read conflict is not on the critical path; the pad regressed time (+8%).
__global__ __launch_bounds__(256, 1) void recur_kernel(
    const bf16* __restrict__ gx, const bf16* __restrict__ Rpk,
    bf16* __restrict__ hs, float* __restrict__ stateOut)
{
  const int n  = blockIdx.x >> 2;       // head
  const int bp = blockIdx.x & 3;        // batch pair
  const int tid = threadIdx.x, w = tid >> 6, l = tid & 63;
  const int b16 = l & 15, fg = l >> 4;
  const int bl  = l & 1;                // local batch (0/1)
  const int r   = l >> 1;               // o within wave's 32-block
  const int q   = r >> 4, r16 = r & 15;
  const int b   = bp*2 + bl;            // global batch
  const int o   = w*32 + r;             // head-local output index [0,128)

  __shared__ __align__(16) bf16 H[2][2][136];        // [buf][bl][o]
  __shared__ __align__(16) float scr[4][2][8][16];   // [wave][bl][tt][r16]
  for (int i = tid; i < 2*2*136; i += 256) ((bf16*)H)[i] = (bf16)0.f;
  __syncthreads();

  // R fragments, register-resident: 8 tiles x 4 k-slices (128 VGPR)
  bf16x8 rf[8][4];
  #pragma unroll
  for (int tt = 0; tt < 8; ++tt)
    #pragma unroll
    for (int kk = 0; kk < 4; ++kk)
      rf[tt][kk] = *(const bf16x8*)&Rpk[(size_t)n*65536 + (size_t)(w*128 + tt*16 + b16)*128 + kk*32 + fg*8];

  // pinned zero accumulator source
  f32x4 zv = {0.f, 0.f, 0.f, 0.f};
  asm volatile("" : "+v"(zv));

  float cS = 0.f, nS = 0.f, mS = 0.f, hv = 0.f;

  // gx element base: j(g) = (w*2+q)*64 + g*16 + r16 ; per-step advance = 512 elems
  const bf16* gxp = gx + (size_t)n * ROWS * 512 + (size_t)b * S_ * 512
                    + (size_t)(w*2 + q) * 64 + r16;
  bf16* hsp = hs + (size_t)b * S_ * D_ + n * HD_ + o;

  bf16 ga[4][4];   // rotating gate-preact buffers [slot][g]
  #pragma unroll
  for (int g = 0; g < 4; ++g) {
    ga[0][g] = gxp[(size_t)0*512 + g*16];
    ga[1][g] = gxp[(size_t)1*512 + g*16];
  }

  auto step = [&](const bf16 (&Hr)[2][136], bf16 (&Hw)[2][136], int s,
                  bf16 (&gU)[4], bf16 (&gF)[4]) {
    // B-operand: h(s-1); cols 0/1 = batches, cols 2-15 duplicate (don't care)
    bf16x8 hf[4];
    #pragma unroll
    for (int kk = 0; kk < 4; ++kk)
      hf[kk] = *(const bf16x8*)&Hr[b16 & 1][kk*32 + fg*8];

    // prefetch gx for s+2
    {
      int sf = (s + 2 < S_) ? s + 2 : 0;
      #pragma unroll
      for (int g = 0; g < 4; ++g)
        gF[g] = gxp[(size_t)sf*512 + g*16];
    }

    // 32 MFMA
    f32x4 acc[8];
    #pragma unroll
    for (int tt = 0; tt < 8; ++tt)
      acc[tt] = __builtin_amdgcn_mfma_f32_16x16x32_bf16(rf[tt][0], hf[0], zv, 0, 0, 0);
    #pragma unroll
    for (int kk = 1; kk < 4; ++kk)
      #pragma unroll
      for (int tt = 0; tt < 8; ++tt)
        acc[tt] = __builtin_amdgcn_mfma_f32_16x16x32_bf16(rf[tt][kk], hf[kk], acc[tt], 0, 0, 0);

    // redistribute via per-wave scratch: 8 ds_write_b128 + 4 ds_read_b32
    if (b16 < 2) {
      #pragma unroll
      for (int tt = 0; tt < 8; ++tt)
        *(f32x4*)&scr[w][b16][tt][fg*4] = acc[tt];
    }
    float pre[4];
    #pragma unroll
    for (int g = 0; g < 4; ++g)
      pre[g] = scr[w][bl][q*4 + g][r16];

    // pointwise, log2 domain — ONE output per lane
    float ir  = pre[0] + (float)gU[0];
    float fr_ = pre[1] + (float)gU[1];
    float zr  = pre[2] + (float)gU[2];
    float og  = pre[3] + (float)gU[3];
    float t   = __builtin_amdgcn_exp2f(-fr_);
    float lfm = mS - __builtin_amdgcn_logf(1.f + t);
    float d   = ir - lfm;
    float e   = __builtin_amdgcn_exp2f(-fabsf(d));
    float iG  = (d >= 0.f) ? 1.f : e;
    float fG  = (d >= 0.f) ? e : 1.f;
    mS = fmaxf(ir, lfm);
    float e2  = __builtin_amdgcn_exp2f(zr);
    float th  = 1.f - 2.f*__builtin_amdgcn_rcpf(e2 + 1.f);
    cS = fG*cS + iG*th;
    nS = fG*nS + iG;
    float eo  = __builtin_amdgcn_exp2f(-og);
    hv = cS * __builtin_amdgcn_rcpf(nS + nS*eo);

    // write h(s): LDS (other buffer) + global stream (never waited on)
    bf16 hb = (bf16)hv;
    Hw[bl][o] = hb;
    hsp[(size_t)s*D_] = hb;

    __builtin_amdgcn_sched_barrier(0);
    __builtin_amdgcn_s_waitcnt(0xC07F);   // lgkmcnt(0); vmcnt untouched
    __builtin_amdgcn_s_barrier();
    __builtin_amdgcn_sched_barrier(0);
  };

  for (int s = 0; s < S_; s += 4) {
    step(H[0], H[1], s,     ga[0], ga[2]);
    step(H[1], H[0], s + 1, ga[1], ga[3]);
    step(H[0], H[1], s + 2, ga[2], ga[0]);
    step(H[1], H[0], s + 3, ga[3], ga[1]);
  }

  {
    const float LN2 = 0.6931471805599453f;
    size_t sb = ((size_t)b*NH_ + n)*HD_ + o;
    stateOut[sb]         = hv;
    stateOut[8192  + sb] = cS;
    stateOut[16384 + sb] = nS;
    stateOut[24576 + sb] = mS * LN2;
  }
}

// ---------------- fused groupnorm + residual + rmsnorm2 ----------------
// writes xr = x + y  into d_out (f32), and xn2 (bf16) for the FFN
__global__ __launch_bounds__(256) void fuse_gn_kernel(
    const bf16* __restrict__ hs, const float* __restrict__ x,
    const float* __restrict__ gnw, const float* __restrict__ r2w,
    float* __restrict__ xr, bf16* __restrict__ xn2)
{
  const int row = blockIdx.x, t = threadIdx.x;
  const size_t base = (size_t)row * D_;
  bf16x4 hraw = ((const bf16x4*)(hs + base))[t];
  float h0 = (float)hraw[0], h1 = (float)hraw[1], h2 = (float)hraw[2], h3 = (float)hraw[3];
  float4 xv = ((const float4*)(x + base))[t];
  float sum = h0 + h1 + h2 + h3;
  float sq  = h0*h0 + h1*h1 + h2*h2 + h3*h3;
  #pragma unroll
  for (int m = 1; m <= 16; m <<= 1) { sum += __shfl_xor(sum, m); sq += __shfl_xor(sq, m); }
  float mu = sum * (1.f/128.f);
  float var = sq * (1.f/128.f) - mu*mu;
  float rstd = rsqrtf(var + 1e-6f);
  float4 gw = ((const float4*)gnw)[t];
  float r0 = xv.x + (h0-mu)*rstd*gw.x;
  float r1 = xv.y + (h1-mu)*rstd*gw.y;
  float r2 = xv.z + (h2-mu)*rstd*gw.z;
  float r3 = xv.w + (h3-mu)*rstd*gw.w;
  ((float4*)(xr + base))[t] = make_float4(r0, r1, r2, r3);
  float p = r0*r0 + r1*r1 + r2*r2 + r3*r3;
  #pragma unroll
  for (int m = 1; m <= 32; m <<= 1) p += __shfl_xor(p, m);
  __shared__ float red[4];
  if ((t & 63) == 0) red[t >> 6] = p;
  __syncthreads();
  float rs = rsqrtf((red[0]+red[1]+red[2]+red[3]) * (1.f/1024.f) + 1e-6f);
  float4 w2 = ((const float4*)r2w)[t];
  bf16x4 o;
  o[0] = (bf16)(r0*rs*w2.x); o[1] = (bf16)(r1*rs*w2.y);
  o[2] = (bf16)(r2*rs*w2.z); o[3] = (bf16)(r3*rs*w2.w);
  ((bf16x4*)(xn2 + base))[t] = o;
}

extern "C" void kernel_launch(void* const* d_in, const int* in_sizes, int n_in,
                              void* d_out, int out_size, void* d_ws, size_t ws_size,
                              hipStream_t stream)
{
  const float* x     = (const float*)d_in[0];
  const float* rms1w = (const float*)d_in[1];
  const float* rms2w = (const float*)d_in[2];
  const float* Wg    = (const float*)d_in[3];
  const float* R     = (const float*)d_in[4];
  const float* bvec  = (const float*)d_in[5];
  const float* gnw   = (const float*)d_in[6];
  const float* Wgate = (const float*)d_in[7];
  const float* Wup   = (const float*)d_in[8];
  const float* Wdown = (const float*)d_in[9];
  float* out = (float*)d_out;
  float* stateOut = out + (size_t)ROWS * D_;

  char* ws = (char*)d_ws;
  size_t off = 0;
  auto alloc = [&](size_t bytes) -> void* {
    void* p = ws + off; off += (bytes + 255) & ~(size_t)255; return p;
  };
  // total ~210.5 MiB
  bf16*  xn     = (bf16*)alloc((size_t)ROWS * D_ * 2);          // 33.5MB (xn, later xn2)
  bf16*  hsbuf  = (bf16*)alloc((size_t)ROWS * D_ * 2);          // 33.5MB
  bf16*  bigbuf = (bf16*)alloc((size_t)NH_ * ROWS * 512 * 2);   // 134MB (gx, later act 92MB)
  bf16*  Wgpk   = (bf16*)alloc(8*512*128*2);
  bf16*  Rpk    = (bf16*)alloc(8*512*128*2);
  float* biaspk = (float*)alloc(8*512*4);
  bf16*  Wgatepk = (bf16*)alloc((size_t)UPP * D_ * 2);
  bf16*  Wuppk   = (bf16*)alloc((size_t)UPP * D_ * 2);
  bf16*  Wdownpk = (bf16*)alloc((size_t)D_ * UPP * 2);

  pack_wgr_kernel<<<2048, 256, 0, stream>>>(Wg, R, bvec, Wgpk, Rpk, biaspk);
  packT_kernel<<<dim3(16, 44), 256, 0, stream>>>(Wgate, Wgatepk, 1024, 2816, 1024, 2752);
  packT_kernel<<<dim3(16, 44), 256, 0, stream>>>(Wup,   Wuppk,   1024, 2816, 1024, 2752);
  packT_kernel<<<dim3(44, 16), 256, 0, stream>>>(Wdown, Wdownpk, 2816, 1024, 2752, 1024);

  rmsnorm1_kernel<<<ROWS, 256, 0, stream>>>(x, rms1w, xn);

  // gx = blockdiag-per-head GEMM + bias (pre-scaled by log2e per gate)
  gemm_bt<0><<<dim3(4, 128, 8), 256, 0, stream>>>(xn, D_, Wgpk, 128,
      nullptr, bigbuf, 512, biaspk, nullptr, 128);

  recur_kernel<<<32, 256, 0, stream>>>(bigbuf, Rpk, hsbuf, stateOut);

  // xr -> d_out, xn2 -> xn
  fuse_gn_kernel<<<ROWS, 256, 0, stream>>>(hsbuf, x, gnw, rms2w, out, xn);

  // act = silu(xn@Wg^T) * (xn@Wu^T), written into bigbuf (gx dead)
  bf16* act = bigbuf;
  gemm_gateup<<<dim3(22, 128), 256, 0, stream>>>(xn, Wgatepk, Wuppk, act);

  // out = xr + act @ Wdown^T   (residual read from d_out, written in place)
  gemm_bt<2><<<dim3(8, 128), 256, 0, stream>>>(act, UPP, Wdownpk, UPP,
      out, nullptr, D_, nullptr, out, UPP);
}